// Round 1
// baseline (1317.566 us; speedup 1.0000x reference)
//
#include <hip/hip_runtime.h>
#include <hip/hip_bf16.h>
#include <cstdint>

// Problem constants (D == H == 128, C == 2)
#define DH 128
#define BN 32   // nodes per block (node kernel)
#define BE 32   // edges per block (edge kernel)

__device__ __forceinline__ float sigmoidf_(float v) {
    return 1.0f / (1.0f + __expf(-v));
}

// Register-tiled GEMM fragment: 4 rows (ty+8i) x 4 cols (tx+32j), NCOL=128.
// in: LDS, row-major with leading dim in_ld (multiple of 4 -> float4 aligned).
// W: global [K][128] row-major (L1/L2 cached, coalesced across tx).
template <int K>
__device__ __forceinline__ void gemm_tile_4x4(const float* in, int in_ld,
                                              const float* __restrict__ W,
                                              float acc[4][4], int tx, int ty)
{
    for (int k = 0; k < K; k += 4) {
        float4 a[4];
        #pragma unroll
        for (int i = 0; i < 4; ++i)
            a[i] = *reinterpret_cast<const float4*>(in + (ty + 8 * i) * in_ld + k);
        #pragma unroll
        for (int kk = 0; kk < 4; ++kk) {
            float w[4];
            #pragma unroll
            for (int j = 0; j < 4; ++j)
                w[j] = W[(k + kk) * DH + tx + 32 * j];
            #pragma unroll
            for (int i = 0; i < 4; ++i) {
                float av = (&a[i].x)[kk];
                #pragma unroll
                for (int j = 0; j < 4; ++j)
                    acc[i][j] = fmaf(av, w[j], acc[i][j]);
            }
        }
    }
}

// ---------------- Node phase: x = sigmoid(z@Wg+bg)*z, z = relu-MLP(h) -------
__global__ __launch_bounds__(256, 2)
void node_mlp_kernel(const float* __restrict__ h,
                     const float* __restrict__ W0, const float* __restrict__ b0,
                     const float* __restrict__ W1, const float* __restrict__ b1,
                     const float* __restrict__ W2, const float* __restrict__ b2,
                     const float* __restrict__ Wg, const float* __restrict__ bg,
                     float* __restrict__ xout, int N)
{
    __shared__ float bufA[BN][DH + 4];
    __shared__ float bufB[BN][DH + 4];
    const int t = threadIdx.x;
    const int tx = t & 31;
    const int ty = t >> 5;
    const int node0 = blockIdx.x * BN;

    // Load 32-node h tile (float4, coalesced: 512B per row)
    #pragma unroll
    for (int i = 0; i < 4; ++i) {
        int r = ty + 8 * i;
        int node = node0 + r;
        float4 v = make_float4(0.f, 0.f, 0.f, 0.f);
        if (node < N) v = reinterpret_cast<const float4*>(h + (size_t)node * DH)[tx];
        *reinterpret_cast<float4*>(&bufA[r][tx * 4]) = v;
    }
    __syncthreads();

    // Layer 0: bufA -> bufB
    {
        float acc[4][4] = {};
        gemm_tile_4x4<DH>(&bufA[0][0], DH + 4, W0, acc, tx, ty);
        #pragma unroll
        for (int j = 0; j < 4; ++j) {
            float bj = b0[tx + 32 * j];
            #pragma unroll
            for (int i = 0; i < 4; ++i)
                bufB[ty + 8 * i][tx + 32 * j] = fmaxf(acc[i][j] + bj, 0.f);
        }
    }
    __syncthreads();
    // Layer 1: bufB -> bufA
    {
        float acc[4][4] = {};
        gemm_tile_4x4<DH>(&bufB[0][0], DH + 4, W1, acc, tx, ty);
        #pragma unroll
        for (int j = 0; j < 4; ++j) {
            float bj = b1[tx + 32 * j];
            #pragma unroll
            for (int i = 0; i < 4; ++i)
                bufA[ty + 8 * i][tx + 32 * j] = fmaxf(acc[i][j] + bj, 0.f);
        }
    }
    __syncthreads();
    // Layer 2: bufA -> bufB
    {
        float acc[4][4] = {};
        gemm_tile_4x4<DH>(&bufA[0][0], DH + 4, W2, acc, tx, ty);
        #pragma unroll
        for (int j = 0; j < 4; ++j) {
            float bj = b2[tx + 32 * j];
            #pragma unroll
            for (int i = 0; i < 4; ++i)
                bufB[ty + 8 * i][tx + 32 * j] = fmaxf(acc[i][j] + bj, 0.f);
        }
    }
    __syncthreads();
    // Gate: x = sigmoid(bufB@Wg + bg) * bufB -> global
    {
        float acc[4][4] = {};
        gemm_tile_4x4<DH>(&bufB[0][0], DH + 4, Wg, acc, tx, ty);
        #pragma unroll
        for (int j = 0; j < 4; ++j) {
            float bj = bg[tx + 32 * j];
            #pragma unroll
            for (int i = 0; i < 4; ++i) {
                int r = ty + 8 * i;
                int node = node0 + r;
                if (node < N) {
                    float xv = bufB[r][tx + 32 * j];
                    float g = sigmoidf_(acc[i][j] + bj);
                    xout[(size_t)node * DH + tx + 32 * j] = g * xv;
                }
            }
        }
    }
}

// ---------------- Edge phase: out = readout(concat(x[src], x[dst])) ---------
__global__ __launch_bounds__(256, 2)
void edge_mlp_kernel(const float* __restrict__ x,
                     const int* __restrict__ src, const int* __restrict__ dst,
                     const float* __restrict__ R0, const float* __restrict__ r0,
                     const float* __restrict__ R1, const float* __restrict__ r1,
                     const float* __restrict__ R2, const float* __restrict__ r2,
                     float* __restrict__ out, int E)
{
    __shared__ float he[BE][2 * DH + 4];   // 33.3 KB
    __shared__ float y1[BE][DH + 4];       // 16.9 KB
    __shared__ float y2[BE][64 + 5];       // 8.8 KB (69: odd stride -> conflict-free col reads)
    const int t = threadIdx.x;
    const int e0 = blockIdx.x * BE;

    // Gather: 64 half-rows of 128 floats; lane loads one float4 (coalesced 512B)
    {
        const int c = t & 31;
        const int hh0 = t >> 5;
        #pragma unroll
        for (int i = 0; i < 8; ++i) {
            int hh = hh0 + 8 * i;            // 0..63
            int eloc = hh >> 1;
            int e = e0 + eloc;
            if (e >= E) e = E - 1;
            int node = (hh & 1) ? dst[e] : src[e];
            float4 v = reinterpret_cast<const float4*>(x + (size_t)node * DH)[c];
            *reinterpret_cast<float4*>(&he[eloc][(hh & 1) * DH + c * 4]) = v;
        }
    }
    __syncthreads();

    // y1 = relu(he @ R0 + r0): [32][128], K=256
    {
        const int tx = t & 31, ty = t >> 5;
        float acc[4][4] = {};
        gemm_tile_4x4<2 * DH>(&he[0][0], 2 * DH + 4, R0, acc, tx, ty);
        #pragma unroll
        for (int j = 0; j < 4; ++j) {
            float bj = r0[tx + 32 * j];
            #pragma unroll
            for (int i = 0; i < 4; ++i)
                y1[ty + 8 * i][tx + 32 * j] = fmaxf(acc[i][j] + bj, 0.f);
        }
    }
    __syncthreads();

    // y2 = relu(y1 @ R1 + r1): [32][64], K=128. Tile: 2 edges x 4 cols.
    {
        const int tx = t & 15, ty = t >> 4;   // ty 0..15
        float acc[2][4] = {};
        for (int k = 0; k < DH; k += 4) {
            float4 a[2];
            #pragma unroll
            for (int i = 0; i < 2; ++i)
                a[i] = *reinterpret_cast<const float4*>(&y1[ty + 16 * i][k]);
            #pragma unroll
            for (int kk = 0; kk < 4; ++kk) {
                float w[4];
                #pragma unroll
                for (int j = 0; j < 4; ++j)
                    w[j] = R1[(k + kk) * 64 + tx + 16 * j];
                #pragma unroll
                for (int i = 0; i < 2; ++i) {
                    float av = (&a[i].x)[kk];
                    #pragma unroll
                    for (int j = 0; j < 4; ++j)
                        acc[i][j] = fmaf(av, w[j], acc[i][j]);
                }
            }
        }
        #pragma unroll
        for (int j = 0; j < 4; ++j) {
            float bj = r1[tx + 16 * j];
            #pragma unroll
            for (int i = 0; i < 2; ++i)
                y2[ty + 16 * i][tx + 16 * j] = fmaxf(acc[i][j] + bj, 0.f);
        }
    }
    __syncthreads();

    // out = y2 @ R2 + r2: [32][2]. One wave handles it (tiny).
    if (t < 64) {
        int eloc = t >> 1, c = t & 1;
        float acc = r2[c];
        #pragma unroll
        for (int k = 0; k < 64; ++k)
            acc = fmaf(y2[eloc][k], R2[k * 2 + c], acc);
        int e = e0 + eloc;
        if (e < E) out[(size_t)e * 2 + c] = acc;
    }
}

extern "C" void kernel_launch(void* const* d_in, const int* in_sizes, int n_in,
                              void* d_out, int out_size, void* d_ws, size_t ws_size,
                              hipStream_t stream)
{
    const float* h  = (const float*)d_in[0];
    const int*   src = (const int*)d_in[1];
    const int*   dst = (const int*)d_in[2];
    const float* W0 = (const float*)d_in[3];
    const float* b0 = (const float*)d_in[4];
    const float* W1 = (const float*)d_in[5];
    const float* b1 = (const float*)d_in[6];
    const float* W2 = (const float*)d_in[7];
    const float* b2 = (const float*)d_in[8];
    const float* Wg = (const float*)d_in[9];
    const float* bg = (const float*)d_in[10];
    const float* R0 = (const float*)d_in[11];
    const float* r0 = (const float*)d_in[12];
    const float* R1 = (const float*)d_in[13];
    const float* r1 = (const float*)d_in[14];
    const float* R2 = (const float*)d_in[15];
    const float* r2 = (const float*)d_in[16];

    const int N = in_sizes[0] / DH;
    const int E = in_sizes[1];

    float* x   = (float*)d_ws;         // [N][128] fp32 = 25.6 MB scratch
    float* out = (float*)d_out;        // [E][2] fp32

    node_mlp_kernel<<<dim3((N + BN - 1) / BN), dim3(256), 0, stream>>>(
        h, W0, b0, W1, b1, W2, b2, Wg, bg, x, N);
    edge_mlp_kernel<<<dim3((E + BE - 1) / BE), dim3(256), 0, stream>>>(
        x, src, dst, R0, r0, R1, r1, R2, r2, out, E);
}

// Round 2
// 195.822 us; speedup vs baseline: 6.7284x; 6.7284x over previous
//
#include <hip/hip_runtime.h>
#include <hip/hip_bf16.h>
#include <cstdint>

typedef _Float16 f16;
typedef _Float16 f16x8 __attribute__((ext_vector_type(8)));
typedef _Float16 f16x4 __attribute__((ext_vector_type(4)));
typedef float    f32x4 __attribute__((ext_vector_type(4)));

#define DH 128

// Packed f16 weight layout (B fragments for v_mfma_f32_16x16x32_f16):
//   packed[((ct*NKS + ks)*64 + lane)*8 + i] = W[ks*32 + (lane>>4)*8 + i][ct*16 + (lane&15)]
// f16-element offsets inside the pack region:
//   pW0:0  pW1:16384  pW2:32768  pWg:49152  pR0:65536(len 32768)  pR1:98304(len 8192)
__global__ void pack_weights_kernel(const float* __restrict__ W0, const float* __restrict__ W1,
                                    const float* __restrict__ W2, const float* __restrict__ Wg,
                                    const float* __restrict__ R0, const float* __restrict__ R1,
                                    f16* __restrict__ pk)
{
    int t = blockIdx.x * 256 + threadIdx.x;
    const float* W; int K, NC, local; f16* dst;
    if      (t < 2048)  { W = W0; K = 128; NC = 128; local = t;         dst = pk + 0;     }
    else if (t < 4096)  { W = W1; K = 128; NC = 128; local = t - 2048;  dst = pk + 16384; }
    else if (t < 6144)  { W = W2; K = 128; NC = 128; local = t - 4096;  dst = pk + 32768; }
    else if (t < 8192)  { W = Wg; K = 128; NC = 128; local = t - 6144;  dst = pk + 49152; }
    else if (t < 12288) { W = R0; K = 256; NC = 128; local = t - 8192;  dst = pk + 65536; }
    else if (t < 13312) { W = R1; K = 128; NC = 64;  local = t - 12288; dst = pk + 98304; }
    else return;
    int lane = local & 63;
    int frag = local >> 6;
    int nks  = K >> 5;
    int ks   = frag % nks;
    int ct   = frag / nks;
    int row0 = ks * 32 + (lane >> 4) * 8;
    int col  = ct * 16 + (lane & 15);
    f16x8 v;
    #pragma unroll
    for (int i = 0; i < 8; ++i) v[i] = (f16)W[(size_t)(row0 + i) * NC + col];
    *(f16x8*)(dst + (size_t)local * 8) = v;
}

// ---------------- Node phase: x = sigmoid(z@Wg+bg)*z, all-MFMA ----------------
// 64 nodes/block, 4 waves; wave w owns rows [16w,16w+16) -> no inter-layer barriers.
__global__ __launch_bounds__(256, 4)
void node_mlp_mfma(const float* __restrict__ h, const f16* __restrict__ pk,
                   const float* __restrict__ b0, const float* __restrict__ b1,
                   const float* __restrict__ b2, const float* __restrict__ bg,
                   f16* __restrict__ xout, int N)
{
    __shared__ f16 zA[64 * 136];
    __shared__ f16 zB[64 * 136];
    const int t = threadIdx.x;
    const int lane = t & 63;
    const int w = t >> 6;
    const int n0 = blockIdx.x * 64;

    // stage h -> zA as f16 (coalesced float4 loads)
    {
        int c4 = t & 31, rr = t >> 5;
        #pragma unroll
        for (int i = 0; i < 8; ++i) {
            int r = rr + 8 * i;
            int node = n0 + r; if (node >= N) node = N - 1;
            float4 v = *(const float4*)(h + (size_t)node * DH + c4 * 4);
            f16x4 o; o[0] = (f16)v.x; o[1] = (f16)v.y; o[2] = (f16)v.z; o[3] = (f16)v.w;
            *(f16x4*)(&zA[r * 136 + c4 * 4]) = o;
        }
    }
    __syncthreads();

    const int lr = lane & 15;   // A row in wave tile / C col
    const int lg = lane >> 4;   // 0..3
    const int arow = w * 16 + lr;

    auto do_layer = [&](const f16* zin, const f16* pw, const float* bias, f16* zout) {
        f16x8 A[4];
        #pragma unroll
        for (int ks = 0; ks < 4; ++ks)
            A[ks] = *(const f16x8*)(&zin[arow * 136 + ks * 32 + lg * 8]);
        #pragma unroll
        for (int ct = 0; ct < 8; ++ct) {
            f32x4 acc = {0.f, 0.f, 0.f, 0.f};
            #pragma unroll
            for (int ks = 0; ks < 4; ++ks) {
                f16x8 B = *(const f16x8*)(pw + ((ct * 4 + ks) * 64 + lane) * 8);
                acc = __builtin_amdgcn_mfma_f32_16x16x32_f16(A[ks], B, acc, 0, 0, 0);
            }
            float bj = bias[ct * 16 + lr];
            #pragma unroll
            for (int r = 0; r < 4; ++r) {
                float vv = fmaxf(acc[r] + bj, 0.f);
                zout[(w * 16 + lg * 4 + r) * 136 + ct * 16 + lr] = (f16)vv;
            }
        }
    };
    do_layer(zA, pk + 0,     b0, zB);
    do_layer(zB, pk + 16384, b1, zA);
    do_layer(zA, pk + 32768, b2, zB);

    // gate: x = sigmoid(zB@Wg + bg) * zB  -> zA (own rows only)
    {
        f16x8 A[4];
        #pragma unroll
        for (int ks = 0; ks < 4; ++ks)
            A[ks] = *(const f16x8*)(&zB[arow * 136 + ks * 32 + lg * 8]);
        #pragma unroll
        for (int ct = 0; ct < 8; ++ct) {
            f32x4 acc = {0.f, 0.f, 0.f, 0.f};
            #pragma unroll
            for (int ks = 0; ks < 4; ++ks) {
                f16x8 B = *(const f16x8*)(pk + 49152 + ((ct * 4 + ks) * 64 + lane) * 8);
                acc = __builtin_amdgcn_mfma_f32_16x16x32_f16(A[ks], B, acc, 0, 0, 0);
            }
            float bj = bg[ct * 16 + lr];
            #pragma unroll
            for (int r = 0; r < 4; ++r) {
                int row = w * 16 + lg * 4 + r;
                float g = acc[r] + bj;
                g = 1.f / (1.f + __expf(-g));
                float z = (float)zB[row * 136 + ct * 16 + lr];
                zA[row * 136 + ct * 16 + lr] = (f16)(g * z);
            }
        }
    }
    __syncthreads();

    // coalesced copy zA -> xout (16B chunks)
    {
        int c8 = t & 15, rr = t >> 4;
        #pragma unroll
        for (int i = 0; i < 4; ++i) {
            int r = rr + 16 * i;
            int node = n0 + r;
            if (node < N) {
                uint4 v = *(const uint4*)(&zA[r * 136 + c8 * 8]);
                *(uint4*)(xout + (size_t)node * DH + c8 * 8) = v;
            }
        }
    }
}

// ---------------- Edge phase: out = readout(concat(x[src], x[dst])) ----------
// 64 edges/block (E % 64 == 0), 4 waves; wave w owns edges [16w,16w+16).
__global__ __launch_bounds__(256, 3)
void edge_mlp_mfma(const f16* __restrict__ x,
                   const int* __restrict__ src, const int* __restrict__ dst,
                   const f16* __restrict__ pk,
                   const float* __restrict__ r0, const float* __restrict__ r1,
                   const float* __restrict__ R2, const float* __restrict__ r2,
                   float* __restrict__ out)
{
    __shared__ __align__(16) char smem[33792 + 17408];   // 50 KB
    f16*   he = (f16*)smem;            // [64][264] f16; src half @0, dst half @136
    float* y2 = (float*)smem;          // [64][65] f32 (aliases he, used after sync)
    f16*   y1 = (f16*)(smem + 33792);  // [64][136] f16

    const int t = threadIdx.x;
    const int lane = t & 63;
    const int w = t >> 6;
    const int e0 = blockIdx.x * 64;

    // gather: 128 node-rows of 256B each, 16B per lane (coalesced)
    {
        int c = t & 15, rr = t >> 4;
        #pragma unroll
        for (int i = 0; i < 8; ++i) {
            int rowidx = rr + 16 * i;                  // 0..127
            int e = e0 + (rowidx >> 1);
            int node = (rowidx & 1) ? dst[e] : src[e];
            uint4 v = *(const uint4*)(x + (size_t)node * DH + c * 8);
            *(uint4*)(&he[(rowidx >> 1) * 264 + (rowidx & 1) * 136 + c * 8]) = v;
        }
    }
    __syncthreads();

    const int lr = lane & 15;
    const int lg = lane >> 4;
    const int erow = w * 16 + lr;

    // L1: y1 = relu(he @ R0 + r0), K=256
    {
        f16x8 A[8];
        #pragma unroll
        for (int ks = 0; ks < 8; ++ks) {
            int bk = (ks < 4) ? ks * 32 : 136 + (ks - 4) * 32;
            A[ks] = *(const f16x8*)(&he[erow * 264 + bk + lg * 8]);
        }
        const f16* pw = pk + 65536;
        #pragma unroll
        for (int ct = 0; ct < 8; ++ct) {
            f32x4 acc = {0.f, 0.f, 0.f, 0.f};
            #pragma unroll
            for (int ks = 0; ks < 8; ++ks) {
                f16x8 B = *(const f16x8*)(pw + ((ct * 8 + ks) * 64 + lane) * 8);
                acc = __builtin_amdgcn_mfma_f32_16x16x32_f16(A[ks], B, acc, 0, 0, 0);
            }
            float bj = r0[ct * 16 + lr];
            #pragma unroll
            for (int r = 0; r < 4; ++r) {
                float vv = fmaxf(acc[r] + bj, 0.f);
                y1[(w * 16 + lg * 4 + r) * 136 + ct * 16 + lr] = (f16)vv;
            }
        }
    }
    __syncthreads();   // he reads done before y2 (alias) writes

    // L2: y2 = relu(y1 @ R1 + r1), K=128, 64 cols, f32 out (stride 65: conflict-free)
    {
        f16x8 A[4];
        #pragma unroll
        for (int ks = 0; ks < 4; ++ks)
            A[ks] = *(const f16x8*)(&y1[erow * 136 + ks * 32 + lg * 8]);
        const f16* pw = pk + 98304;
        #pragma unroll
        for (int ct = 0; ct < 4; ++ct) {
            f32x4 acc = {0.f, 0.f, 0.f, 0.f};
            #pragma unroll
            for (int ks = 0; ks < 4; ++ks) {
                f16x8 B = *(const f16x8*)(pw + ((ct * 4 + ks) * 64 + lane) * 8);
                acc = __builtin_amdgcn_mfma_f32_16x16x32_f16(A[ks], B, acc, 0, 0, 0);
            }
            float bj = r1[ct * 16 + lr];
            #pragma unroll
            for (int r = 0; r < 4; ++r)
                y2[(w * 16 + lg * 4 + r) * 65 + ct * 16 + lr] = fmaxf(acc[r] + bj, 0.f);
        }
    }
    __syncthreads();

    // L3: out = y2 @ R2 + r2 (fp32 VALU, K=64, C=2)
    if (t < 128) {
        int el = t >> 1, c = t & 1;
        float acc = r2[c];
        #pragma unroll
        for (int k = 0; k < 64; ++k)
            acc = fmaf(y2[el * 65 + k], R2[k * 2 + c], acc);
        out[(size_t)(e0 + el) * 2 + c] = acc;
    }
}

extern "C" void kernel_launch(void* const* d_in, const int* in_sizes, int n_in,
                              void* d_out, int out_size, void* d_ws, size_t ws_size,
                              hipStream_t stream)
{
    const float* h   = (const float*)d_in[0];
    const int*   src = (const int*)d_in[1];
    const int*   dst = (const int*)d_in[2];
    const float* W0  = (const float*)d_in[3];
    const float* b0  = (const float*)d_in[4];
    const float* W1  = (const float*)d_in[5];
    const float* b1  = (const float*)d_in[6];
    const float* W2  = (const float*)d_in[7];
    const float* b2  = (const float*)d_in[8];
    const float* Wg  = (const float*)d_in[9];
    const float* bg  = (const float*)d_in[10];
    const float* R0  = (const float*)d_in[11];
    const float* r0  = (const float*)d_in[12];
    const float* R1  = (const float*)d_in[13];
    const float* r1  = (const float*)d_in[14];
    const float* R2  = (const float*)d_in[15];
    const float* r2  = (const float*)d_in[16];

    const int N = in_sizes[0] / DH;
    const int E = in_sizes[1];

    f16* ws16 = (f16*)d_ws;
    f16* x_f16 = ws16;                       // N*128 f16 = 12.8 MB
    f16* pk    = ws16 + (size_t)N * DH;      // 106,496 f16 packed weights

    pack_weights_kernel<<<dim3(52), dim3(256), 0, stream>>>(W0, W1, W2, Wg, R0, R1, pk);
    node_mlp_mfma<<<dim3((N + 63) / 64), dim3(256), 0, stream>>>(
        h, pk, b0, b1, b2, bg, x_f16, N);
    edge_mlp_mfma<<<dim3(E / 64), dim3(256), 0, stream>>>(
        x_f16, src, dst, pk, r0, r1, R2, r2, (float*)d_out);
}

// Round 4
// 115.697 us; speedup vs baseline: 11.3881x; 1.6925x over previous
//
#include <hip/hip_runtime.h>
#include <hip/hip_bf16.h>
#include <cstdint>

typedef _Float16 f16;
typedef _Float16 f16x8 __attribute__((ext_vector_type(8)));
typedef _Float16 f16x4 __attribute__((ext_vector_type(4)));
typedef float    f32x4 __attribute__((ext_vector_type(4)));

#define DH 128

// Packed f16 weight layout (fragments for v_mfma_f32_16x16x32_f16; the A- and
// B-operand per-lane layouts are identical: lane holds outer-index (lane&15),
// 8 contiguous k at (lane>>4)*8 within each 32-k step):
//   packed[((ct*NKS + ks)*64 + lane)*8 + i] = W[rb + ks*32 + (lane>>4)*8 + i][ct*16 + (lane&15)]
#define PK_W0   0
#define PK_W1   16384
#define PK_W2   32768
#define PK_WG   49152
#define PK_R0A  65536   /* R0 rows   0..127 (applied to src feats) */
#define PK_R0B  81920   /* R0 rows 128..255 (applied to dst feats) */
#define PK_R1   98304   /* R1 128x64 */
#define PK_TOTAL 106496

__global__ void pack_weights_kernel(const float* __restrict__ W0, const float* __restrict__ W1,
                                    const float* __restrict__ W2, const float* __restrict__ Wg,
                                    const float* __restrict__ R0, const float* __restrict__ R1,
                                    f16* __restrict__ pk)
{
    int t = blockIdx.x * 256 + threadIdx.x;
    const float* W; int K, NC, local, rb = 0; f16* dst;
    if      (t < 2048)  { W = W0; K = 128; NC = 128; local = t;          dst = pk + PK_W0;  }
    else if (t < 4096)  { W = W1; K = 128; NC = 128; local = t - 2048;   dst = pk + PK_W1;  }
    else if (t < 6144)  { W = W2; K = 128; NC = 128; local = t - 4096;   dst = pk + PK_W2;  }
    else if (t < 8192)  { W = Wg; K = 128; NC = 128; local = t - 6144;   dst = pk + PK_WG;  }
    else if (t < 10240) { W = R0; K = 128; NC = 128; local = t - 8192;   dst = pk + PK_R0A; }
    else if (t < 12288) { W = R0; K = 128; NC = 128; local = t - 10240;  dst = pk + PK_R0B; rb = 128; }
    else if (t < 13312) { W = R1; K = 128; NC = 64;  local = t - 12288;  dst = pk + PK_R1;  }
    else return;
    int lane = local & 63;
    int frag = local >> 6;
    int nks  = K >> 5;
    int ks   = frag % nks;
    int ct   = frag / nks;
    int row0 = rb + ks * 32 + ((lane >> 4) << 3);
    int col  = ct * 16 + (lane & 15);
    f16x8 v;
    #pragma unroll
    for (int i = 0; i < 8; ++i) v[i] = (f16)W[(size_t)(row0 + i) * NC + col];
    *(f16x8*)(dst + (size_t)local * 8) = v;
}

// ---------------- Node phase: x = sigmoid(z@Wg+bg)*z; u = x@R0a + r0; v = x@R0b
// 64 nodes/block, 4 waves; wave w owns rows [16w,16w+16) -> no inter-layer barriers.
__global__ __launch_bounds__(256, 4)
void node_mlp_mfma(const float* __restrict__ h, const f16* __restrict__ pk,
                   const float* __restrict__ b0, const float* __restrict__ b1,
                   const float* __restrict__ b2, const float* __restrict__ bg,
                   const float* __restrict__ r0,
                   f16* __restrict__ ug, f16* __restrict__ vg, int N)
{
    __shared__ f16 zA[64 * 136];
    __shared__ f16 zB[64 * 136];
    const int t = threadIdx.x;
    const int lane = t & 63;
    const int w = t >> 6;
    const int n0 = blockIdx.x * 64;

    // stage h -> zA as f16 (coalesced float4 loads)
    {
        int c4 = t & 31, rr = t >> 5;
        #pragma unroll
        for (int i = 0; i < 8; ++i) {
            int r = rr + 8 * i;
            int node = n0 + r; if (node >= N) node = N - 1;
            float4 v = *(const float4*)(h + (size_t)node * DH + c4 * 4);
            f16x4 o; o[0] = (f16)v.x; o[1] = (f16)v.y; o[2] = (f16)v.z; o[3] = (f16)v.w;
            *(f16x4*)(&zA[r * 136 + c4 * 4]) = o;
        }
    }
    __syncthreads();

    const int lr = lane & 15;
    const int lg = lane >> 4;
    const int arow = w * 16 + lr;

    auto do_layer = [&](const f16* zin, const f16* pw, const float* bias, f16* zout) {
        f16x8 A[4];
        #pragma unroll
        for (int ks = 0; ks < 4; ++ks)
            A[ks] = *(const f16x8*)(&zin[arow * 136 + ks * 32 + lg * 8]);
        #pragma unroll
        for (int ct = 0; ct < 8; ++ct) {
            f32x4 acc = {0.f, 0.f, 0.f, 0.f};
            #pragma unroll
            for (int ks = 0; ks < 4; ++ks) {
                f16x8 B = *(const f16x8*)(pw + ((ct * 4 + ks) * 64 + lane) * 8);
                acc = __builtin_amdgcn_mfma_f32_16x16x32_f16(A[ks], B, acc, 0, 0, 0);
            }
            float bj = bias[ct * 16 + lr];
            #pragma unroll
            for (int r = 0; r < 4; ++r) {
                float vv = fmaxf(acc[r] + bj, 0.f);
                zout[(w * 16 + lg * 4 + r) * 136 + ct * 16 + lr] = (f16)vv;
            }
        }
    };
    // linear (no relu), bias optional
    auto do_linear = [&](const f16* zin, const f16* pw, const float* bias, f16* zout) {
        f16x8 A[4];
        #pragma unroll
        for (int ks = 0; ks < 4; ++ks)
            A[ks] = *(const f16x8*)(&zin[arow * 136 + ks * 32 + lg * 8]);
        #pragma unroll
        for (int ct = 0; ct < 8; ++ct) {
            f32x4 acc = {0.f, 0.f, 0.f, 0.f};
            #pragma unroll
            for (int ks = 0; ks < 4; ++ks) {
                f16x8 B = *(const f16x8*)(pw + ((ct * 4 + ks) * 64 + lane) * 8);
                acc = __builtin_amdgcn_mfma_f32_16x16x32_f16(A[ks], B, acc, 0, 0, 0);
            }
            float bj = bias ? bias[ct * 16 + lr] : 0.f;
            #pragma unroll
            for (int r = 0; r < 4; ++r)
                zout[(w * 16 + lg * 4 + r) * 136 + ct * 16 + lr] = (f16)(acc[r] + bj);
        }
    };
    auto copy_out = [&](const f16* zsrc, f16* gdst) {
        int c8 = t & 15, rr = t >> 4;
        #pragma unroll
        for (int i = 0; i < 4; ++i) {
            int r = rr + 16 * i;
            int node = n0 + r;
            if (node < N) {
                uint4 vv = *(const uint4*)(&zsrc[r * 136 + c8 * 8]);
                *(uint4*)(gdst + (size_t)node * DH + c8 * 8) = vv;
            }
        }
    };

    do_layer(zA, pk + PK_W0, b0, zB);
    do_layer(zB, pk + PK_W1, b1, zA);
    do_layer(zA, pk + PK_W2, b2, zB);

    // gate: x = sigmoid(zB@Wg + bg) * zB  -> zA (own rows only)
    {
        f16x8 A[4];
        #pragma unroll
        for (int ks = 0; ks < 4; ++ks)
            A[ks] = *(const f16x8*)(&zB[arow * 136 + ks * 32 + lg * 8]);
        #pragma unroll
        for (int ct = 0; ct < 8; ++ct) {
            f32x4 acc = {0.f, 0.f, 0.f, 0.f};
            #pragma unroll
            for (int ks = 0; ks < 4; ++ks) {
                f16x8 B = *(const f16x8*)(pk + PK_WG + ((ct * 4 + ks) * 64 + lane) * 8);
                acc = __builtin_amdgcn_mfma_f32_16x16x32_f16(A[ks], B, acc, 0, 0, 0);
            }
            float bj = bg[ct * 16 + lr];
            #pragma unroll
            for (int r = 0; r < 4; ++r) {
                int row = w * 16 + lg * 4 + r;
                float gv = acc[r] + bj;
                gv = 1.f / (1.f + __expf(-gv));
                float z = (float)zB[row * 136 + ct * 16 + lr];
                zA[row * 136 + ct * 16 + lr] = (f16)(gv * z);
            }
        }
    }
    // u = x @ R0a + r0  (bias folded; edge kernel computes relu(u+v))
    do_linear(zA, pk + PK_R0A, r0, zB);
    __syncthreads();
    copy_out(zB, ug);
    __syncthreads();
    // v = x @ R0b
    do_linear(zA, pk + PK_R0B, nullptr, zB);
    __syncthreads();
    copy_out(zB, vg);
}

// ---------------- Edge phase: out = (relu(relu(u[src]+v[dst]) @ R1 + r1)) @ R2 + r2
// Zero LDS. Wave-independent: 16 edges per wave-iteration, grid-stride.
// R1 fragments persist in VGPRs; gather lands directly in MFMA fragment regs.
__global__ __launch_bounds__(256, 2)
void edge_mlp_v3(const f16* __restrict__ u, const f16* __restrict__ v,
                 const int* __restrict__ src, const int* __restrict__ dst,
                 const f16* __restrict__ pk,
                 const float* __restrict__ r1, const float* __restrict__ R2,
                 const float* __restrict__ r2,
                 float* __restrict__ out, int E, int ngroups, int nwaves)
{
    const int t = threadIdx.x;
    const int lane = t & 63;
    const int lr = lane & 15, lg = lane >> 4;
    const int wid = (int)((blockIdx.x * blockDim.x + t) >> 6);

    // R1^T fragments (MFMA A operand), wave-uniform, held in registers
    f16x8 Bw[16];
    #pragma unroll
    for (int f = 0; f < 16; ++f)
        Bw[f] = *(const f16x8*)(pk + PK_R1 + ((size_t)(f * 64 + lane)) * 8);

    f32x4 r1f[4];
    #pragma unroll
    for (int ct = 0; ct < 4; ++ct)
        r1f[ct] = *(const f32x4*)(r1 + ct * 16 + lg * 4);

    float R2f0[16], R2f1[16];
    #pragma unroll
    for (int ct = 0; ct < 4; ++ct)
        #pragma unroll
        for (int r = 0; r < 4; ++r) {
            int k = ct * 16 + lg * 4 + r;
            R2f0[ct * 4 + r] = R2[k * 2 + 0];
            R2f1[ct * 4 + r] = R2[k * 2 + 1];
        }
    const float ob0 = r2[0], ob1 = r2[1];

    int g = wid;
    if (g >= ngroups) return;

    // prologue: idx[g] -> uv[g] issued; idx[g+nw] issued
    int e0 = g * 16 + lr; if (e0 >= E) e0 = E - 1;
    int sc = src[e0], dc = dst[e0];
    f16x8 Uc[4], Vc[4];
    {
        const f16* ur = u + (size_t)sc * DH + lg * 8;
        const f16* vr = v + (size_t)dc * DH + lg * 8;
        #pragma unroll
        for (int ks = 0; ks < 4; ++ks) {
            Uc[ks] = *(const f16x8*)(ur + ks * 32);
            Vc[ks] = *(const f16x8*)(vr + ks * 32);
        }
    }
    int sn = 0, dn = 0;
    if (g + nwaves < ngroups) {
        int en = (g + nwaves) * 16 + lr; if (en >= E) en = E - 1;
        sn = src[en]; dn = dst[en];
    }

    while (g < ngroups) {
        const int gnext = g + nwaves;
        // issue next gather (1 iteration of latency hiding)
        f16x8 Un[4], Vn[4];
        if (gnext < ngroups) {
            const f16* ur = u + (size_t)sn * DH + lg * 8;
            const f16* vr = v + (size_t)dn * DH + lg * 8;
            #pragma unroll
            for (int ks = 0; ks < 4; ++ks) {
                Un[ks] = *(const f16x8*)(ur + ks * 32);
                Vn[ks] = *(const f16x8*)(vr + ks * 32);
            }
        }
        // prefetch idx two iterations ahead
        int g2 = g + 2 * nwaves;
        int s2 = 0, d2 = 0;
        if (g2 < ngroups) {
            int e2 = g2 * 16 + lr; if (e2 >= E) e2 = E - 1;
            s2 = src[e2]; d2 = dst[e2];
        }

        // y1 fragments: relu(u + v)  (r0 folded into u)
        f16x8 A[4];
        #pragma unroll
        for (int ks = 0; ks < 4; ++ks) {
            f16x8 s = Uc[ks] + Vc[ks];
            #pragma unroll
            for (int i = 0; i < 8; ++i) s[i] = s[i] > (f16)0 ? s[i] : (f16)0;
            A[ks] = s;
        }

        // L2 GEMM (swapped): D[outcol][edge], lane holds edge (lane&15)
        f32x4 a0 = {0.f,0.f,0.f,0.f}, a1 = {0.f,0.f,0.f,0.f};
        f32x4 a2 = {0.f,0.f,0.f,0.f}, a3 = {0.f,0.f,0.f,0.f};
        #pragma unroll
        for (int ks = 0; ks < 4; ++ks) {
            a0 = __builtin_amdgcn_mfma_f32_16x16x32_f16(Bw[0*4+ks], A[ks], a0, 0, 0, 0);
            a1 = __builtin_amdgcn_mfma_f32_16x16x32_f16(Bw[1*4+ks], A[ks], a1, 0, 0, 0);
            a2 = __builtin_amdgcn_mfma_f32_16x16x32_f16(Bw[2*4+ks], A[ks], a2, 0, 0, 0);
            a3 = __builtin_amdgcn_mfma_f32_16x16x32_f16(Bw[3*4+ks], A[ks], a3, 0, 0, 0);
        }

        // bias + relu + L3 partial dot. NOTE: partials start at 0; the r2 bias
        // is added exactly once by the writing lane (lg==0) AFTER the lane
        // reduction (round-3 bug: bias was summed 4x across lg groups).
        float p0 = 0.f, p1 = 0.f;
        #pragma unroll
        for (int r = 0; r < 4; ++r) {
            float y;
            y = fmaxf(a0[r] + r1f[0][r], 0.f); p0 = fmaf(y, R2f0[0*4+r], p0); p1 = fmaf(y, R2f1[0*4+r], p1);
            y = fmaxf(a1[r] + r1f[1][r], 0.f); p0 = fmaf(y, R2f0[1*4+r], p0); p1 = fmaf(y, R2f1[1*4+r], p1);
            y = fmaxf(a2[r] + r1f[2][r], 0.f); p0 = fmaf(y, R2f0[2*4+r], p0); p1 = fmaf(y, R2f1[2*4+r], p1);
            y = fmaxf(a3[r] + r1f[3][r], 0.f); p0 = fmaf(y, R2f0[3*4+r], p0); p1 = fmaf(y, R2f1[3*4+r], p1);
        }
        // reduce over the 4 lg groups
        float q;
        q = __shfl_xor(p0, 16); p0 += q;
        q = __shfl_xor(p0, 32); p0 += q;
        q = __shfl_xor(p1, 16); p1 += q;
        q = __shfl_xor(p1, 32); p1 += q;
        int eo = g * 16 + lr;
        if (lg == 0 && eo < E)
            *(float2*)(out + (size_t)eo * 2) = make_float2(p0 + ob0, p1 + ob1);

        // rotate pipeline registers
        #pragma unroll
        for (int ks = 0; ks < 4; ++ks) { Uc[ks] = Un[ks]; Vc[ks] = Vn[ks]; }
        sc = sn; dc = dn; sn = s2; dn = d2;
        g = gnext;
    }
}

extern "C" void kernel_launch(void* const* d_in, const int* in_sizes, int n_in,
                              void* d_out, int out_size, void* d_ws, size_t ws_size,
                              hipStream_t stream)
{
    const float* h   = (const float*)d_in[0];
    const int*   src = (const int*)d_in[1];
    const int*   dst = (const int*)d_in[2];
    const float* W0  = (const float*)d_in[3];
    const float* b0  = (const float*)d_in[4];
    const float* W1  = (const float*)d_in[5];
    const float* b1  = (const float*)d_in[6];
    const float* W2  = (const float*)d_in[7];
    const float* b2  = (const float*)d_in[8];
    const float* Wg  = (const float*)d_in[9];
    const float* bg  = (const float*)d_in[10];
    const float* R0  = (const float*)d_in[11];
    const float* r0  = (const float*)d_in[12];
    const float* R1  = (const float*)d_in[13];
    const float* r1  = (const float*)d_in[14];
    const float* R2  = (const float*)d_in[15];
    const float* r2  = (const float*)d_in[16];

    const int N = in_sizes[0] / DH;
    const int E = in_sizes[1];

    f16* pk = (f16*)d_ws;                        // 208 KB packed weights
    f16* ug = pk + PK_TOTAL;                     // N*128 f16
    f16* vg = ug + (size_t)N * DH;               // N*128 f16

    pack_weights_kernel<<<dim3(52), dim3(256), 0, stream>>>(W0, W1, W2, Wg, R0, R1, pk);
    node_mlp_mfma<<<dim3((N + 63) / 64), dim3(256), 0, stream>>>(
        h, pk, b0, b1, b2, bg, r0, ug, vg, N);

    const int ngroups = (E + 15) / 16;
    const int nblocks = 1024;
    const int nwaves  = nblocks * 4;
    edge_mlp_v3<<<dim3(nblocks), dim3(256), 0, stream>>>(
        ug, vg, src, dst, pk, r1, R2, r2, (float*)d_out, E, ngroups, nwaves);
}

// Round 5
// 103.541 us; speedup vs baseline: 12.7251x; 1.1174x over previous
//
#include <hip/hip_runtime.h>
#include <hip/hip_bf16.h>
#include <cstdint>

typedef _Float16 f16;
typedef _Float16 f16x8 __attribute__((ext_vector_type(8)));
typedef _Float16 f16x4 __attribute__((ext_vector_type(4)));
typedef float    f32x4 __attribute__((ext_vector_type(4)));

#define DH 128

// Packed f16 weight layout (fragments for v_mfma_f32_16x16x32_f16; the A- and
// B-operand per-lane layouts are identical: lane holds outer-index (lane&15),
// 8 contiguous k at (lane>>4)*8 within each 32-k step):
//   packed[((ct*NKS + ks)*64 + lane)*8 + i] = W[rb + ks*32 + (lane>>4)*8 + i][ct*16 + (lane&15)]
#define PK_W0   0
#define PK_W1   16384
#define PK_W2   32768
#define PK_WG   49152
#define PK_R0A  65536   /* R0 rows   0..127 (applied to src feats) */
#define PK_R0B  81920   /* R0 rows 128..255 (applied to dst feats) */
#define PK_R1   98304   /* R1 128x64 */
#define PK_TOTAL 106496

__global__ void pack_weights_kernel(const float* __restrict__ W0, const float* __restrict__ W1,
                                    const float* __restrict__ W2, const float* __restrict__ Wg,
                                    const float* __restrict__ R0, const float* __restrict__ R1,
                                    f16* __restrict__ pk)
{
    int t = blockIdx.x * 256 + threadIdx.x;
    const float* W; int K, NC, local, rb = 0; f16* dst;
    if      (t < 2048)  { W = W0; K = 128; NC = 128; local = t;          dst = pk + PK_W0;  }
    else if (t < 4096)  { W = W1; K = 128; NC = 128; local = t - 2048;   dst = pk + PK_W1;  }
    else if (t < 6144)  { W = W2; K = 128; NC = 128; local = t - 4096;   dst = pk + PK_W2;  }
    else if (t < 8192)  { W = Wg; K = 128; NC = 128; local = t - 6144;   dst = pk + PK_WG;  }
    else if (t < 10240) { W = R0; K = 128; NC = 128; local = t - 8192;   dst = pk + PK_R0A; }
    else if (t < 12288) { W = R0; K = 128; NC = 128; local = t - 10240;  dst = pk + PK_R0B; rb = 128; }
    else if (t < 13312) { W = R1; K = 128; NC = 64;  local = t - 12288;  dst = pk + PK_R1;  }
    else return;
    int lane = local & 63;
    int frag = local >> 6;
    int nks  = K >> 5;
    int ks   = frag % nks;
    int ct   = frag / nks;
    int row0 = rb + ks * 32 + ((lane >> 4) << 3);
    int col  = ct * 16 + (lane & 15);
    f16x8 v;
    #pragma unroll
    for (int i = 0; i < 8; ++i) v[i] = (f16)W[(size_t)(row0 + i) * NC + col];
    *(f16x8*)(dst + (size_t)local * 8) = v;
}

// ---------------- Node phase: x = sigmoid(z@Wg+bg)*z; u = x@R0a + r0; v = x@R0b
// 128 nodes/block, 4 waves; wave w owns rows [32w,32w+32) as TWO 16-row tiles
// sharing every B-fragment load (2 MFMAs per B read -> half the weight traffic).
// No inter-layer barriers (row slices are wave-private).
__global__ __launch_bounds__(256, 2)
void node_mlp_mfma(const float* __restrict__ h, const f16* __restrict__ pk,
                   const float* __restrict__ b0, const float* __restrict__ b1,
                   const float* __restrict__ b2, const float* __restrict__ bg,
                   const float* __restrict__ r0,
                   f16* __restrict__ ug, f16* __restrict__ vg, int N)
{
    __shared__ f16 zA[128 * 136];
    __shared__ f16 zB[128 * 136];
    const int t = threadIdx.x;
    const int lane = t & 63;
    const int w = t >> 6;
    const int n0 = blockIdx.x * 128;

    // stage h -> zA as f16 (coalesced float4 loads); 128 rows x 32 chunks
    {
        int c4 = t & 31, rr = t >> 5;
        #pragma unroll
        for (int i = 0; i < 16; ++i) {
            int r = rr + 8 * i;
            int node = n0 + r; if (node >= N) node = N - 1;
            float4 v = *(const float4*)(h + (size_t)node * DH + c4 * 4);
            f16x4 o; o[0] = (f16)v.x; o[1] = (f16)v.y; o[2] = (f16)v.z; o[3] = (f16)v.w;
            *(f16x4*)(&zA[r * 136 + c4 * 4]) = o;
        }
    }
    __syncthreads();

    const int lr = lane & 15;
    const int lg = lane >> 4;
    const int rowA = w * 32 + lr;        // A-frag row, tile 0
    // tile 1 row = rowA + 16

    // one layer: two 16-row tiles, B loaded once per (ct,ks)
    auto do_layer = [&](const f16* zin, const f16* pw, const float* bias,
                        bool do_relu, f16* zout) {
        f16x8 A0[4], A1[4];
        #pragma unroll
        for (int ks = 0; ks < 4; ++ks) {
            A0[ks] = *(const f16x8*)(&zin[rowA * 136 + ks * 32 + lg * 8]);
            A1[ks] = *(const f16x8*)(&zin[(rowA + 16) * 136 + ks * 32 + lg * 8]);
        }
        #pragma unroll
        for (int ct = 0; ct < 8; ++ct) {
            f32x4 acc0 = {0.f, 0.f, 0.f, 0.f};
            f32x4 acc1 = {0.f, 0.f, 0.f, 0.f};
            #pragma unroll
            for (int ks = 0; ks < 4; ++ks) {
                f16x8 B = *(const f16x8*)(pw + ((ct * 4 + ks) * 64 + lane) * 8);
                acc0 = __builtin_amdgcn_mfma_f32_16x16x32_f16(A0[ks], B, acc0, 0, 0, 0);
                acc1 = __builtin_amdgcn_mfma_f32_16x16x32_f16(A1[ks], B, acc1, 0, 0, 0);
            }
            float bj = bias ? bias[ct * 16 + lr] : 0.f;
            #pragma unroll
            for (int r = 0; r < 4; ++r) {
                float v0 = acc0[r] + bj;
                float v1 = acc1[r] + bj;
                if (do_relu) { v0 = fmaxf(v0, 0.f); v1 = fmaxf(v1, 0.f); }
                zout[(w * 32 + lg * 4 + r) * 136 + ct * 16 + lr] = (f16)v0;
                zout[(w * 32 + 16 + lg * 4 + r) * 136 + ct * 16 + lr] = (f16)v1;
            }
        }
    };
    auto copy_out = [&](const f16* zsrc, f16* gdst) {
        int c8 = t & 15, rr = t >> 4;
        #pragma unroll
        for (int i = 0; i < 8; ++i) {
            int r = rr + 16 * i;
            int node = n0 + r;
            if (node < N) {
                uint4 vv = *(const uint4*)(&zsrc[r * 136 + c8 * 8]);
                *(uint4*)(gdst + (size_t)node * DH + c8 * 8) = vv;
            }
        }
    };

    do_layer(zA, pk + PK_W0, b0, true, zB);
    do_layer(zB, pk + PK_W1, b1, true, zA);
    do_layer(zA, pk + PK_W2, b2, true, zB);

    // gate: x = sigmoid(zB@Wg + bg) * zB -> zA (own rows only)
    {
        f16x8 A0[4], A1[4];
        #pragma unroll
        for (int ks = 0; ks < 4; ++ks) {
            A0[ks] = *(const f16x8*)(&zB[rowA * 136 + ks * 32 + lg * 8]);
            A1[ks] = *(const f16x8*)(&zB[(rowA + 16) * 136 + ks * 32 + lg * 8]);
        }
        #pragma unroll
        for (int ct = 0; ct < 8; ++ct) {
            f32x4 acc0 = {0.f, 0.f, 0.f, 0.f};
            f32x4 acc1 = {0.f, 0.f, 0.f, 0.f};
            #pragma unroll
            for (int ks = 0; ks < 4; ++ks) {
                f16x8 B = *(const f16x8*)(pk + PK_WG + ((ct * 4 + ks) * 64 + lane) * 8);
                acc0 = __builtin_amdgcn_mfma_f32_16x16x32_f16(A0[ks], B, acc0, 0, 0, 0);
                acc1 = __builtin_amdgcn_mfma_f32_16x16x32_f16(A1[ks], B, acc1, 0, 0, 0);
            }
            float bj = bg[ct * 16 + lr];
            #pragma unroll
            for (int r = 0; r < 4; ++r) {
                int row0 = w * 32 + lg * 4 + r;
                int row1 = row0 + 16;
                float g0 = acc0[r] + bj, g1 = acc1[r] + bj;
                g0 = 1.f / (1.f + __expf(-g0));
                g1 = 1.f / (1.f + __expf(-g1));
                float z0 = (float)zB[row0 * 136 + ct * 16 + lr];
                float z1 = (float)zB[row1 * 136 + ct * 16 + lr];
                zA[row0 * 136 + ct * 16 + lr] = (f16)(g0 * z0);
                zA[row1 * 136 + ct * 16 + lr] = (f16)(g1 * z1);
            }
        }
    }
    // u = x @ R0a + r0  (bias folded; edge kernel computes relu(u+v))
    do_layer(zA, pk + PK_R0A, r0, false, zB);
    __syncthreads();
    copy_out(zB, ug);
    __syncthreads();
    // v = x @ R0b
    do_layer(zA, pk + PK_R0B, nullptr, false, zB);
    __syncthreads();
    copy_out(zB, vg);
}

// ---------------- Edge phase: out = (relu(relu(u[src]+v[dst]) @ R1 + r1)) @ R2 + r2
// Zero LDS. Wave-independent: 16 edges per wave-iteration, grid-stride.
// R1 fragments persist in VGPRs; gather lands directly in MFMA fragment regs.
__global__ __launch_bounds__(256, 2)
void edge_mlp_v3(const f16* __restrict__ u, const f16* __restrict__ v,
                 const int* __restrict__ src, const int* __restrict__ dst,
                 const f16* __restrict__ pk,
                 const float* __restrict__ r1, const float* __restrict__ R2,
                 const float* __restrict__ r2,
                 float* __restrict__ out, int E, int ngroups, int nwaves)
{
    const int t = threadIdx.x;
    const int lane = t & 63;
    const int lr = lane & 15, lg = lane >> 4;
    const int wid = (int)((blockIdx.x * blockDim.x + t) >> 6);

    // R1^T fragments (MFMA A operand), wave-uniform, held in registers
    f16x8 Bw[16];
    #pragma unroll
    for (int f = 0; f < 16; ++f)
        Bw[f] = *(const f16x8*)(pk + PK_R1 + ((size_t)(f * 64 + lane)) * 8);

    f32x4 r1f[4];
    #pragma unroll
    for (int ct = 0; ct < 4; ++ct)
        r1f[ct] = *(const f32x4*)(r1 + ct * 16 + lg * 4);

    float R2f0[16], R2f1[16];
    #pragma unroll
    for (int ct = 0; ct < 4; ++ct)
        #pragma unroll
        for (int r = 0; r < 4; ++r) {
            int k = ct * 16 + lg * 4 + r;
            R2f0[ct * 4 + r] = R2[k * 2 + 0];
            R2f1[ct * 4 + r] = R2[k * 2 + 1];
        }
    const float ob0 = r2[0], ob1 = r2[1];

    int g = wid;
    if (g >= ngroups) return;

    // prologue: idx[g] -> uv[g] issued; idx[g+nw] issued
    int e0 = g * 16 + lr; if (e0 >= E) e0 = E - 1;
    int sc = src[e0], dc = dst[e0];
    f16x8 Uc[4], Vc[4];
    {
        const f16* ur = u + (size_t)sc * DH + lg * 8;
        const f16* vr = v + (size_t)dc * DH + lg * 8;
        #pragma unroll
        for (int ks = 0; ks < 4; ++ks) {
            Uc[ks] = *(const f16x8*)(ur + ks * 32);
            Vc[ks] = *(const f16x8*)(vr + ks * 32);
        }
    }
    int sn = 0, dn = 0;
    if (g + nwaves < ngroups) {
        int en = (g + nwaves) * 16 + lr; if (en >= E) en = E - 1;
        sn = src[en]; dn = dst[en];
    }

    while (g < ngroups) {
        const int gnext = g + nwaves;
        // issue next gather (1 iteration of latency hiding)
        f16x8 Un[4], Vn[4];
        if (gnext < ngroups) {
            const f16* ur = u + (size_t)sn * DH + lg * 8;
            const f16* vr = v + (size_t)dn * DH + lg * 8;
            #pragma unroll
            for (int ks = 0; ks < 4; ++ks) {
                Un[ks] = *(const f16x8*)(ur + ks * 32);
                Vn[ks] = *(const f16x8*)(vr + ks * 32);
            }
        }
        // prefetch idx two iterations ahead
        int g2 = g + 2 * nwaves;
        int s2 = 0, d2 = 0;
        if (g2 < ngroups) {
            int e2 = g2 * 16 + lr; if (e2 >= E) e2 = E - 1;
            s2 = src[e2]; d2 = dst[e2];
        }

        // y1 fragments: relu(u + v)  (r0 folded into u)
        f16x8 A[4];
        #pragma unroll
        for (int ks = 0; ks < 4; ++ks) {
            f16x8 s = Uc[ks] + Vc[ks];
            #pragma unroll
            for (int i = 0; i < 8; ++i) s[i] = s[i] > (f16)0 ? s[i] : (f16)0;
            A[ks] = s;
        }

        // L2 GEMM (swapped): D[outcol][edge], lane holds edge (lane&15)
        f32x4 a0 = {0.f,0.f,0.f,0.f}, a1 = {0.f,0.f,0.f,0.f};
        f32x4 a2 = {0.f,0.f,0.f,0.f}, a3 = {0.f,0.f,0.f,0.f};
        #pragma unroll
        for (int ks = 0; ks < 4; ++ks) {
            a0 = __builtin_amdgcn_mfma_f32_16x16x32_f16(Bw[0*4+ks], A[ks], a0, 0, 0, 0);
            a1 = __builtin_amdgcn_mfma_f32_16x16x32_f16(Bw[1*4+ks], A[ks], a1, 0, 0, 0);
            a2 = __builtin_amdgcn_mfma_f32_16x16x32_f16(Bw[2*4+ks], A[ks], a2, 0, 0, 0);
            a3 = __builtin_amdgcn_mfma_f32_16x16x32_f16(Bw[3*4+ks], A[ks], a3, 0, 0, 0);
        }

        // bias + relu + L3 partial dot. Partials start at 0; the r2 bias is
        // added exactly once by the writing lane (lg==0) AFTER the reduction.
        float p0 = 0.f, p1 = 0.f;
        #pragma unroll
        for (int r = 0; r < 4; ++r) {
            float y;
            y = fmaxf(a0[r] + r1f[0][r], 0.f); p0 = fmaf(y, R2f0[0*4+r], p0); p1 = fmaf(y, R2f1[0*4+r], p1);
            y = fmaxf(a1[r] + r1f[1][r], 0.f); p0 = fmaf(y, R2f0[1*4+r], p0); p1 = fmaf(y, R2f1[1*4+r], p1);
            y = fmaxf(a2[r] + r1f[2][r], 0.f); p0 = fmaf(y, R2f0[2*4+r], p0); p1 = fmaf(y, R2f1[2*4+r], p1);
            y = fmaxf(a3[r] + r1f[3][r], 0.f); p0 = fmaf(y, R2f0[3*4+r], p0); p1 = fmaf(y, R2f1[3*4+r], p1);
        }
        // reduce over the 4 lg groups
        float q;
        q = __shfl_xor(p0, 16); p0 += q;
        q = __shfl_xor(p0, 32); p0 += q;
        q = __shfl_xor(p1, 16); p1 += q;
        q = __shfl_xor(p1, 32); p1 += q;
        int eo = g * 16 + lr;
        if (lg == 0 && eo < E)
            *(float2*)(out + (size_t)eo * 2) = make_float2(p0 + ob0, p1 + ob1);

        // rotate pipeline registers
        #pragma unroll
        for (int ks = 0; ks < 4; ++ks) { Uc[ks] = Un[ks]; Vc[ks] = Vn[ks]; }
        sc = sn; dc = dn; sn = s2; dn = d2;
        g = gnext;
    }
}

extern "C" void kernel_launch(void* const* d_in, const int* in_sizes, int n_in,
                              void* d_out, int out_size, void* d_ws, size_t ws_size,
                              hipStream_t stream)
{
    const float* h   = (const float*)d_in[0];
    const int*   src = (const int*)d_in[1];
    const int*   dst = (const int*)d_in[2];
    const float* W0  = (const float*)d_in[3];
    const float* b0  = (const float*)d_in[4];
    const float* W1  = (const float*)d_in[5];
    const float* b1  = (const float*)d_in[6];
    const float* W2  = (const float*)d_in[7];
    const float* b2  = (const float*)d_in[8];
    const float* Wg  = (const float*)d_in[9];
    const float* bg  = (const float*)d_in[10];
    const float* R0  = (const float*)d_in[11];
    const float* r0  = (const float*)d_in[12];
    const float* R1  = (const float*)d_in[13];
    const float* r1  = (const float*)d_in[14];
    const float* R2  = (const float*)d_in[15];
    const float* r2  = (const float*)d_in[16];

    const int N = in_sizes[0] / DH;
    const int E = in_sizes[1];

    f16* pk = (f16*)d_ws;                        // 208 KB packed weights
    f16* ug = pk + PK_TOTAL;                     // N*128 f16
    f16* vg = ug + (size_t)N * DH;               // N*128 f16

    pack_weights_kernel<<<dim3(52), dim3(256), 0, stream>>>(W0, W1, W2, Wg, R0, R1, pk);
    node_mlp_mfma<<<dim3((N + 127) / 128), dim3(256), 0, stream>>>(
        h, pk, b0, b1, b2, bg, r0, ug, vg, N);

    const int ngroups = (E + 15) / 16;
    const int nblocks = 2048;                    // 2x resident capacity -> backfill
    const int nwaves  = nblocks * 4;
    edge_mlp_v3<<<dim3(nblocks), dim3(256), 0, stream>>>(
        ug, vg, src, dst, pk, r1, R2, r2, (float*)d_out, E, ngroups, nwaves);
}